// Round 10
// baseline (53.231 us; speedup 1.0000x reference)
//
#include <hip/hip_runtime.h>

#define TLEN   500000
#define NITER  100
#define DHALF  6                  // band half-width; W_d ~ 0.135/d! -> d=7 term ~2.7e-5
#define NOFF   (2*DHALF+1)        // 13 offsets
#define STRIP  20                 // edge strip width
#define EWIN   32                 // edge window (32 cols x 8 rows = 256 lanes)
#define CT     256                // conv threads = cols per block
#define NCONV  ((TLEN - 2*STRIP + CT - 1) / CT)   // 1954

// ============ K1: band weights (blocks 0-12) + edge strips (blocks 13,14) ============
// One lane per (column-state, output-row i). Each lane keeps only row i of
// Cm/P/Fu (23 coefficients) in registers; column states live in a ping-ponged
// LDS buffer with one barrier per iteration.
__global__ __launch_bounds__(256) void band_and_edges(
    const float* __restrict__ xs, const float* __restrict__ ys,
    const float* __restrict__ F, const float* __restrict__ H,
    const float* __restrict__ Q, const float* __restrict__ R,
    const float* __restrict__ gam,
    float* __restrict__ wout,            // d_ws: 12*13*8 floats, layout [k][d][i]
    float* __restrict__ out)
{
  __shared__ double dQaug[8][16];
  __shared__ double dRaug[4][8];
  __shared__ double dFtQi[64], dHtRi[32], dA1[64], dB2[64];
  __shared__ float fmats[224];
  __shared__ __align__(16) float st[2][34][8];   // ping-pong column states

  const int tid = threadIdx.x;
  const int b   = blockIdx.x;
  const int r8  = (tid >> 3) & 7;
  const int c8  = tid & 7;

  // ---------- double-precision operator construction (redundant per block) ----------
  if (tid < 64) {
    dQaug[r8][c8]     = (double)Q[r8*8 + c8];
    dQaug[r8][c8 + 8] = (c8 == r8) ? 1.0 : 0.0;
  } else if (tid < 96) {
    int t = tid - 64, rr = t >> 3, cr = t & 7;
    dRaug[rr][cr] = (cr < 4) ? (double)R[rr*4 + cr] : ((cr - 4 == rr) ? 1.0 : 0.0);
  }
  __syncthreads();
  for (int col = 0; col < 8; ++col) {      // Gauss-Jordan (Q,R SPD: no pivoting)
    double piv = 1, fq = 0, p1 = 0, p2 = 0, m1 = 0, m2 = 0;
    double rpiv = 1, frr = 0, pr = 0, mr = 0;
    const bool doQ = tid < 64;
    const bool doR = (tid >= 64 && tid < 96 && col < 4);
    if (doQ) {
      piv = dQaug[col][col]; fq = dQaug[r8][col];
      p1 = dQaug[col][c8];   p2 = dQaug[col][c8 + 8];
      m1 = dQaug[r8][c8];    m2 = dQaug[r8][c8 + 8];
    }
    if (doR) {
      int t = tid - 64, rr = t >> 3, cr = t & 7;
      rpiv = dRaug[col][col]; frr = dRaug[rr][col];
      pr = dRaug[col][cr];    mr = dRaug[rr][cr];
    }
    __syncthreads();
    if (doQ) {
      dQaug[r8][c8]     = (r8 == col) ? m1 / piv : m1 - fq * (p1 / piv);
      dQaug[r8][c8 + 8] = (r8 == col) ? m2 / piv : m2 - fq * (p2 / piv);
    }
    if (doR) {
      int t = tid - 64, rr = t >> 3, cr = t & 7;
      dRaug[rr][cr] = (rr == col) ? mr / rpiv : mr - frr * (pr / rpiv);
    }
    __syncthreads();
  }
  if (tid < 64) {
    double s = 0.0;
    #pragma unroll
    for (int k = 0; k < 8; ++k) s += (double)F[k*8 + r8] * dQaug[k][c8 + 8];
    dFtQi[r8*8 + c8] = s;
    dA1[r8*8 + c8] = (c8 == 0) ? 0.0 : -dQaug[r8][c8 + 8];
  } else if (tid < 96) {
    int t = tid - 64, i = t >> 2, j = t & 3;
    double s = 0.0;
    #pragma unroll
    for (int k = 0; k < 4; ++k) s += (double)H[k*8 + i] * dRaug[k][j + 4];
    dHtRi[i*4 + j] = s;
  }
  __syncthreads();
  if (tid < 64) dB2[r8*8 + c8] = (c8 == 7) ? 0.0 : dFtQi[r8*8 + c8];
  __syncthreads();
  {
    const double g = (double)gam[0];
    if (tid < 64) {
      double sp = 0.0;
      #pragma unroll
      for (int k = 0; k < 8; ++k) sp -= dA1[r8*8 + k] * (double)F[k*8 + c8];
      double t2 = dA1[r8*8 + c8];
      #pragma unroll
      for (int k = 0; k < 8; ++k) t2 -= dB2[r8*8 + k] * (double)F[k*8 + c8];
      #pragma unroll
      for (int k = 0; k < 4; ++k) t2 -= dHtRi[r8*4 + k] * (double)H[k*8 + c8];
      fmats[       c8*8 + r8] = (float)(((r8 == c8) ? 1.0 : 0.0) + g * t2);
      fmats[ 64 +  c8*8 + r8] = (float)(g * sp);
      fmats[128 +  c8*8 + r8] = (float)(g * dB2[r8*8 + c8]);
    } else if (tid < 96) {
      int t = tid - 64, i = t >> 2, j = t & 3;
      fmats[192 + j*8 + i] = (float)(g * dHtRi[i*4 + j]);
    }
  }
  __syncthreads();

  // ---------- per-lane coefficient rows (23 registers) ----------
  const int i = tid & 7;       // output row owned by this lane
  const int g = tid >> 3;      // group: slot (band) or column (edge)
  float cmr[8], pmr[8], fur[7];
  #pragma unroll
  for (int k = 0; k < 8; ++k) {
    cmr[k] = fmats[       k*8 + i];
    pmr[k] = fmats[ 64 +  k*8 + i];
    if (k < 7) fur[k] = fmats[128 + k*8 + i];
  }
  float* const stf = (float*)st;
  const int BUF = 34*8;

  if (b < 12) {
    // ---- band recurrence: W'_s = Cm*W_s + P*W_{s+1} + Fu*W_{s-1}, guards at 0, NOFF+1 ----
    const int c = b;                    // source column 0..11 (8..11 = y columns)
    const bool act = tid < NOFF*8;      // 13 slots x 8 rows
    const int s = g + 1;                // slot 1..13
    for (int idx = tid; idx < 2*BUF; idx += 256) stf[idx] = 0.0f;
    __syncthreads();
    if (act && c < 8 && s == DHALF + 1 && i == c) st[0][s][i] = 1.0f;   // W_0 = I
    const float seed = (act && c >= 8 && s == DHALF + 1) ? fmats[192 + (c - 8)*8 + i] : 0.0f;
    __syncthreads();
    int p = 0;
    float last = 0.0f;
    #pragma unroll 1
    for (int it = 0; it < NITER; ++it) {
      if (act) {
        const float* sp_ = stf + p*BUF;
        const float4 o0 = *(const float4*)(sp_ + s*8);
        const float4 o1 = *(const float4*)(sp_ + s*8 + 4);
        const float4 u0 = *(const float4*)(sp_ + (s + 1)*8);
        const float4 u1 = *(const float4*)(sp_ + (s + 1)*8 + 4);
        const float4 d0 = *(const float4*)(sp_ + (s - 1)*8);
        const float4 d1 = *(const float4*)(sp_ + (s - 1)*8 + 4);
        float a0 = seed, a1 = 0.0f, a2 = 0.0f;
        a0 = fmaf(cmr[0], o0.x, a0); a0 = fmaf(cmr[1], o0.y, a0);
        a0 = fmaf(cmr[2], o0.z, a0); a0 = fmaf(cmr[3], o0.w, a0);
        a0 = fmaf(cmr[4], o1.x, a0); a0 = fmaf(cmr[5], o1.y, a0);
        a0 = fmaf(cmr[6], o1.z, a0); a0 = fmaf(cmr[7], o1.w, a0);
        a1 = fmaf(pmr[0], u0.x, a1); a1 = fmaf(pmr[1], u0.y, a1);
        a1 = fmaf(pmr[2], u0.z, a1); a1 = fmaf(pmr[3], u0.w, a1);
        a1 = fmaf(pmr[4], u1.x, a1); a1 = fmaf(pmr[5], u1.y, a1);
        a1 = fmaf(pmr[6], u1.z, a1); a1 = fmaf(pmr[7], u1.w, a1);
        a2 = fmaf(fur[0], d0.x, a2); a2 = fmaf(fur[1], d0.y, a2);
        a2 = fmaf(fur[2], d0.z, a2); a2 = fmaf(fur[3], d0.w, a2);
        a2 = fmaf(fur[4], d1.x, a2); a2 = fmaf(fur[5], d1.y, a2);
        a2 = fmaf(fur[6], d1.z, a2);
        last = a0 + a1 + a2;
        stf[(p^1)*BUF + s*8 + i] = last;
      }
      __syncthreads();
      p ^= 1;
    }
    if (act) wout[(c*NOFF + (s - 1))*8 + i] = last;   // layout [k][d][i]
    return;
  }

  // ---- edge strips: 32 columns x 8 rows, true clamp at the outer boundary ----
  const bool left = (b == 12);
  const int col  = g;                                    // 0..31
  const int gcol = left ? col : (TLEN - EWIN + col);
  const int sL = (col > 0) ? col - 1 : 0;                // replicate at window edge
  const int sR = (col < EWIN - 1) ? col + 1 : EWIN - 1;
  const float xv = xs[i*TLEN + gcol];
  float gyv;
  {
    gyv = fmats[192 +      i] * ys[0*TLEN + gcol];
    gyv = fmaf(fmats[192 +  8 + i], ys[1*TLEN + gcol], gyv);
    gyv = fmaf(fmats[192 + 16 + i], ys[2*TLEN + gcol], gyv);
    gyv = fmaf(fmats[192 + 24 + i], ys[3*TLEN + gcol], gyv);
  }
  st[0][col][i] = xv;
  __syncthreads();
  int p = 0;
  float last = xv;
  #pragma unroll 1
  for (int it = 0; it < NITER; ++it) {
    const float* sp_ = stf + p*BUF;
    const float4 o0 = *(const float4*)(sp_ + col*8);
    const float4 o1 = *(const float4*)(sp_ + col*8 + 4);
    const float4 l0 = *(const float4*)(sp_ + sL*8);      // x_{t-1}
    const float4 l1 = *(const float4*)(sp_ + sL*8 + 4);
    const float4 q0 = *(const float4*)(sp_ + sR*8);      // x_{t+1}
    const float4 q1 = *(const float4*)(sp_ + sR*8 + 4);
    float a0 = gyv, a1 = 0.0f, a2 = 0.0f;
    a0 = fmaf(cmr[0], o0.x, a0); a0 = fmaf(cmr[1], o0.y, a0);
    a0 = fmaf(cmr[2], o0.z, a0); a0 = fmaf(cmr[3], o0.w, a0);
    a0 = fmaf(cmr[4], o1.x, a0); a0 = fmaf(cmr[5], o1.y, a0);
    a0 = fmaf(cmr[6], o1.z, a0); a0 = fmaf(cmr[7], o1.w, a0);
    a1 = fmaf(pmr[0], l0.x, a1); a1 = fmaf(pmr[1], l0.y, a1);
    a1 = fmaf(pmr[2], l0.z, a1); a1 = fmaf(pmr[3], l0.w, a1);
    a1 = fmaf(pmr[4], l1.x, a1); a1 = fmaf(pmr[5], l1.y, a1);
    a1 = fmaf(pmr[6], l1.z, a1); a1 = fmaf(pmr[7], l1.w, a1);
    a2 = fmaf(fur[0], q0.x, a2); a2 = fmaf(fur[1], q0.y, a2);
    a2 = fmaf(fur[2], q0.z, a2); a2 = fmaf(fur[3], q0.w, a2);
    a2 = fmaf(fur[4], q1.x, a2); a2 = fmaf(fur[5], q1.y, a2);
    a2 = fmaf(fur[6], q1.z, a2);
    last = a0 + a1 + a2;
    stf[(p^1)*BUF + col*8 + i] = last;
    __syncthreads();
    p ^= 1;
  }
  if (left ? (col < STRIP) : (col >= EWIN - STRIP)) out[i*TLEN + gcol] = last;
}

// ============ K2: interior band convolution — direct global, no LDS ============
// Window reads for covered cols stay in [STRIP-DHALF, TLEN-STRIP+DHALF) — in
// bounds by construction; tail threads clamp col for address safety and mask
// their stores.
__global__ __launch_bounds__(CT) void kgm_conv(
    const float* __restrict__ xs, const float* __restrict__ ys,
    const float* __restrict__ wq, float* __restrict__ out)
{
  const int tid  = threadIdx.x;
  const int ocol = STRIP + blockIdx.x * CT + tid;
  const int col  = (ocol < TLEN - STRIP) ? ocol : (TLEN - STRIP - 1);

  float acc[8] = {0,0,0,0,0,0,0,0};
  #pragma unroll
  for (int k = 0; k < 12; ++k) {
    const float* src = (k < 8) ? (xs + k*TLEN + col) : (ys + (k-8)*TLEN + col);
    const float* wk  = wq + k*(NOFF*8);
    float z[NOFF];
    #pragma unroll
    for (int d = 0; d < NOFF; ++d) z[d] = src[d - DHALF];
    #pragma unroll
    for (int d = 0; d < NOFF; ++d) {
      #pragma unroll
      for (int i = 0; i < 8; ++i)
        acc[i] = fmaf(wk[d*8 + i], z[d], acc[i]);
    }
  }

  if (ocol < TLEN - STRIP) {
    #pragma unroll
    for (int i = 0; i < 8; ++i) out[i*TLEN + ocol] = acc[i];
  }
}

extern "C" void kernel_launch(void* const* d_in, const int* in_sizes, int n_in,
                              void* d_out, int out_size, void* d_ws, size_t ws_size,
                              hipStream_t stream)
{
  (void)in_sizes; (void)n_in; (void)out_size; (void)ws_size;
  const float* xs = (const float*)d_in[0];
  const float* ys = (const float*)d_in[1];
  const float* F  = (const float*)d_in[2];
  const float* H  = (const float*)d_in[3];
  const float* Q  = (const float*)d_in[4];
  const float* R  = (const float*)d_in[5];
  const float* ga = (const float*)d_in[6];
  float* ws  = (float*)d_ws;     // [0, 12*13*8): band weights, layout [k][d][i]
  float* out = (float*)d_out;
  band_and_edges<<<14, 256, 0, stream>>>(xs, ys, F, H, Q, R, ga, ws, out);
  kgm_conv<<<NCONV, CT, 0, stream>>>(xs, ys, ws, out);
}

// Round 11
// 51.872 us; speedup vs baseline: 1.0262x; 1.0262x over previous
//
#include <hip/hip_runtime.h>

#define TLEN   500000
#define NITER  100
#define DHALF  6                  // band half-width; W_d ~ 0.135/d! -> d=7 term ~2.7e-5
#define NOFF   (2*DHALF+1)        // 13 offsets
#define STRIP  20                 // edge strip width
#define EWIN   32                 // edge window (32 cols x 8 rows = 256 lanes)
#define CT     256                // conv threads
#define CCPT   4                  // cols per thread
#define NCONV  (((TLEN - 2*STRIP)/CCPT + CT - 1) / CT)   // 489

// ============ K1: band weights (blocks 0-12) + edge strips (blocks 13,14) ============
// One lane per (column-state, output-row i). Each lane keeps only row i of
// Cm/P/Fu (23 coefficients) in registers; column states live in a ping-ponged
// LDS buffer with one barrier per iteration.
__global__ __launch_bounds__(256) void band_and_edges(
    const float* __restrict__ xs, const float* __restrict__ ys,
    const float* __restrict__ F, const float* __restrict__ H,
    const float* __restrict__ Q, const float* __restrict__ R,
    const float* __restrict__ gam,
    float* __restrict__ wout,            // d_ws: 12*13*8 floats, layout [k][d][i]
    float* __restrict__ out)
{
  __shared__ double dQaug[8][16];
  __shared__ double dRaug[4][8];
  __shared__ double dFtQi[64], dHtRi[32], dA1[64], dB2[64];
  __shared__ float fmats[224];
  __shared__ __align__(16) float st[2][34][8];   // ping-pong column states

  const int tid = threadIdx.x;
  const int b   = blockIdx.x;
  const int r8  = (tid >> 3) & 7;
  const int c8  = tid & 7;

  // ---------- double-precision operator construction (redundant per block) ----------
  if (tid < 64) {
    dQaug[r8][c8]     = (double)Q[r8*8 + c8];
    dQaug[r8][c8 + 8] = (c8 == r8) ? 1.0 : 0.0;
  } else if (tid < 96) {
    int t = tid - 64, rr = t >> 3, cr = t & 7;
    dRaug[rr][cr] = (cr < 4) ? (double)R[rr*4 + cr] : ((cr - 4 == rr) ? 1.0 : 0.0);
  }
  __syncthreads();
  for (int col = 0; col < 8; ++col) {      // Gauss-Jordan (Q,R SPD: no pivoting)
    double piv = 1, fq = 0, p1 = 0, p2 = 0, m1 = 0, m2 = 0;
    double rpiv = 1, frr = 0, pr = 0, mr = 0;
    const bool doQ = tid < 64;
    const bool doR = (tid >= 64 && tid < 96 && col < 4);
    if (doQ) {
      piv = dQaug[col][col]; fq = dQaug[r8][col];
      p1 = dQaug[col][c8];   p2 = dQaug[col][c8 + 8];
      m1 = dQaug[r8][c8];    m2 = dQaug[r8][c8 + 8];
    }
    if (doR) {
      int t = tid - 64, rr = t >> 3, cr = t & 7;
      rpiv = dRaug[col][col]; frr = dRaug[rr][col];
      pr = dRaug[col][cr];    mr = dRaug[rr][cr];
    }
    __syncthreads();
    if (doQ) {
      dQaug[r8][c8]     = (r8 == col) ? m1 / piv : m1 - fq * (p1 / piv);
      dQaug[r8][c8 + 8] = (r8 == col) ? m2 / piv : m2 - fq * (p2 / piv);
    }
    if (doR) {
      int t = tid - 64, rr = t >> 3, cr = t & 7;
      dRaug[rr][cr] = (rr == col) ? mr / rpiv : mr - frr * (pr / rpiv);
    }
    __syncthreads();
  }
  if (tid < 64) {
    double s = 0.0;
    #pragma unroll
    for (int k = 0; k < 8; ++k) s += (double)F[k*8 + r8] * dQaug[k][c8 + 8];
    dFtQi[r8*8 + c8] = s;
    dA1[r8*8 + c8] = (c8 == 0) ? 0.0 : -dQaug[r8][c8 + 8];
  } else if (tid < 96) {
    int t = tid - 64, i = t >> 2, j = t & 3;
    double s = 0.0;
    #pragma unroll
    for (int k = 0; k < 4; ++k) s += (double)H[k*8 + i] * dRaug[k][j + 4];
    dHtRi[i*4 + j] = s;
  }
  __syncthreads();
  if (tid < 64) dB2[r8*8 + c8] = (c8 == 7) ? 0.0 : dFtQi[r8*8 + c8];
  __syncthreads();
  {
    const double g = (double)gam[0];
    if (tid < 64) {
      double sp = 0.0;
      #pragma unroll
      for (int k = 0; k < 8; ++k) sp -= dA1[r8*8 + k] * (double)F[k*8 + c8];
      double t2 = dA1[r8*8 + c8];
      #pragma unroll
      for (int k = 0; k < 8; ++k) t2 -= dB2[r8*8 + k] * (double)F[k*8 + c8];
      #pragma unroll
      for (int k = 0; k < 4; ++k) t2 -= dHtRi[r8*4 + k] * (double)H[k*8 + c8];
      fmats[       c8*8 + r8] = (float)(((r8 == c8) ? 1.0 : 0.0) + g * t2);
      fmats[ 64 +  c8*8 + r8] = (float)(g * sp);
      fmats[128 +  c8*8 + r8] = (float)(g * dB2[r8*8 + c8]);
    } else if (tid < 96) {
      int t = tid - 64, i = t >> 2, j = t & 3;
      fmats[192 + j*8 + i] = (float)(g * dHtRi[i*4 + j]);
    }
  }
  __syncthreads();

  // ---------- per-lane coefficient rows (23 registers) ----------
  const int i = tid & 7;       // output row owned by this lane
  const int g = tid >> 3;      // group: slot (band) or column (edge)
  float cmr[8], pmr[8], fur[7];
  #pragma unroll
  for (int k = 0; k < 8; ++k) {
    cmr[k] = fmats[       k*8 + i];
    pmr[k] = fmats[ 64 +  k*8 + i];
    if (k < 7) fur[k] = fmats[128 + k*8 + i];
  }
  float* const stf = (float*)st;
  const int BUF = 34*8;

  if (b < 12) {
    // ---- band recurrence: W'_s = Cm*W_s + P*W_{s+1} + Fu*W_{s-1}, guards at 0, NOFF+1 ----
    const int c = b;                    // source column 0..11 (8..11 = y columns)
    const bool act = tid < NOFF*8;      // 13 slots x 8 rows
    const int s = g + 1;                // slot 1..13
    for (int idx = tid; idx < 2*BUF; idx += 256) stf[idx] = 0.0f;
    __syncthreads();
    if (act && c < 8 && s == DHALF + 1 && i == c) st[0][s][i] = 1.0f;   // W_0 = I
    const float seed = (act && c >= 8 && s == DHALF + 1) ? fmats[192 + (c - 8)*8 + i] : 0.0f;
    __syncthreads();
    int p = 0;
    float last = 0.0f;
    #pragma unroll 1
    for (int it = 0; it < NITER; ++it) {
      if (act) {
        const float* sp_ = stf + p*BUF;
        const float4 o0 = *(const float4*)(sp_ + s*8);
        const float4 o1 = *(const float4*)(sp_ + s*8 + 4);
        const float4 u0 = *(const float4*)(sp_ + (s + 1)*8);
        const float4 u1 = *(const float4*)(sp_ + (s + 1)*8 + 4);
        const float4 d0 = *(const float4*)(sp_ + (s - 1)*8);
        const float4 d1 = *(const float4*)(sp_ + (s - 1)*8 + 4);
        float a0 = seed, a1 = 0.0f, a2 = 0.0f;
        a0 = fmaf(cmr[0], o0.x, a0); a0 = fmaf(cmr[1], o0.y, a0);
        a0 = fmaf(cmr[2], o0.z, a0); a0 = fmaf(cmr[3], o0.w, a0);
        a0 = fmaf(cmr[4], o1.x, a0); a0 = fmaf(cmr[5], o1.y, a0);
        a0 = fmaf(cmr[6], o1.z, a0); a0 = fmaf(cmr[7], o1.w, a0);
        a1 = fmaf(pmr[0], u0.x, a1); a1 = fmaf(pmr[1], u0.y, a1);
        a1 = fmaf(pmr[2], u0.z, a1); a1 = fmaf(pmr[3], u0.w, a1);
        a1 = fmaf(pmr[4], u1.x, a1); a1 = fmaf(pmr[5], u1.y, a1);
        a1 = fmaf(pmr[6], u1.z, a1); a1 = fmaf(pmr[7], u1.w, a1);
        a2 = fmaf(fur[0], d0.x, a2); a2 = fmaf(fur[1], d0.y, a2);
        a2 = fmaf(fur[2], d0.z, a2); a2 = fmaf(fur[3], d0.w, a2);
        a2 = fmaf(fur[4], d1.x, a2); a2 = fmaf(fur[5], d1.y, a2);
        a2 = fmaf(fur[6], d1.z, a2);
        last = a0 + a1 + a2;
        stf[(p^1)*BUF + s*8 + i] = last;
      }
      __syncthreads();
      p ^= 1;
    }
    if (act) wout[(c*NOFF + (s - 1))*8 + i] = last;   // layout [k][d][i]
    return;
  }

  // ---- edge strips: 32 columns x 8 rows, true clamp at the outer boundary ----
  const bool left = (b == 12);
  const int col  = g;                                    // 0..31
  const int gcol = left ? col : (TLEN - EWIN + col);
  const int sL = (col > 0) ? col - 1 : 0;                // replicate at window edge
  const int sR = (col < EWIN - 1) ? col + 1 : EWIN - 1;
  const float xv = xs[i*TLEN + gcol];
  float gyv;
  {
    gyv = fmats[192 +      i] * ys[0*TLEN + gcol];
    gyv = fmaf(fmats[192 +  8 + i], ys[1*TLEN + gcol], gyv);
    gyv = fmaf(fmats[192 + 16 + i], ys[2*TLEN + gcol], gyv);
    gyv = fmaf(fmats[192 + 24 + i], ys[3*TLEN + gcol], gyv);
  }
  st[0][col][i] = xv;
  __syncthreads();
  int p = 0;
  float last = xv;
  #pragma unroll 1
  for (int it = 0; it < NITER; ++it) {
    const float* sp_ = stf + p*BUF;
    const float4 o0 = *(const float4*)(sp_ + col*8);
    const float4 o1 = *(const float4*)(sp_ + col*8 + 4);
    const float4 l0 = *(const float4*)(sp_ + sL*8);      // x_{t-1}
    const float4 l1 = *(const float4*)(sp_ + sL*8 + 4);
    const float4 q0 = *(const float4*)(sp_ + sR*8);      // x_{t+1}
    const float4 q1 = *(const float4*)(sp_ + sR*8 + 4);
    float a0 = gyv, a1 = 0.0f, a2 = 0.0f;
    a0 = fmaf(cmr[0], o0.x, a0); a0 = fmaf(cmr[1], o0.y, a0);
    a0 = fmaf(cmr[2], o0.z, a0); a0 = fmaf(cmr[3], o0.w, a0);
    a0 = fmaf(cmr[4], o1.x, a0); a0 = fmaf(cmr[5], o1.y, a0);
    a0 = fmaf(cmr[6], o1.z, a0); a0 = fmaf(cmr[7], o1.w, a0);
    a1 = fmaf(pmr[0], l0.x, a1); a1 = fmaf(pmr[1], l0.y, a1);
    a1 = fmaf(pmr[2], l0.z, a1); a1 = fmaf(pmr[3], l0.w, a1);
    a1 = fmaf(pmr[4], l1.x, a1); a1 = fmaf(pmr[5], l1.y, a1);
    a1 = fmaf(pmr[6], l1.z, a1); a1 = fmaf(pmr[7], l1.w, a1);
    a2 = fmaf(fur[0], q0.x, a2); a2 = fmaf(fur[1], q0.y, a2);
    a2 = fmaf(fur[2], q0.z, a2); a2 = fmaf(fur[3], q0.w, a2);
    a2 = fmaf(fur[4], q1.x, a2); a2 = fmaf(fur[5], q1.y, a2);
    a2 = fmaf(fur[6], q1.z, a2);
    last = a0 + a1 + a2;
    stf[(p^1)*BUF + col*8 + i] = last;
    __syncthreads();
    p ^= 1;
  }
  if (left ? (col < STRIP) : (col >= EWIN - STRIP)) out[i*TLEN + gcol] = last;
}

// ============ K2: interior band convolution — CCPT=4, aligned float4 windows ============
// Each thread: 4 output cols x 8 rows. Per k: 5 x global_load_dwordx4 (20-float
// window, 16B-aligned) + one weight s_load batch amortized over 416 FMAs.
__global__ __launch_bounds__(CT) void kgm_conv(
    const float* __restrict__ xs, const float* __restrict__ ys,
    const float* __restrict__ wq, float* __restrict__ out)
{
  const int tid  = threadIdx.x;
  const int ocol = STRIP + (blockIdx.x * CT + tid) * CCPT;
  const int col0 = (ocol <= TLEN - STRIP - CCPT) ? ocol : (TLEN - STRIP - CCPT);

  float4 acc[8];
  #pragma unroll
  for (int i = 0; i < 8; ++i) acc[i] = make_float4(0.f, 0.f, 0.f, 0.f);

  #pragma unroll 1
  for (int k = 0; k < 12; ++k) {
    const float* src = ((k < 8) ? (xs + k*TLEN) : (ys + (k-8)*TLEN)) + col0;
    // 20-float window [col0-8, col0+12); col0 % 4 == 0 so all loads 16B-aligned
    float z[20];
    #pragma unroll
    for (int j = 0; j < 5; ++j) {
      float4 v = *(const float4*)(src - 8 + 4*j);
      z[4*j] = v.x; z[4*j + 1] = v.y; z[4*j + 2] = v.z; z[4*j + 3] = v.w;
    }
    const float* wk = wq + k*(NOFF*8);
    #pragma unroll
    for (int d = 0; d < NOFF; ++d) {
      #pragma unroll
      for (int i = 0; i < 8; ++i) {
        const float w = wk[d*8 + i];
        acc[i].x = fmaf(w, z[d + 2], acc[i].x);   // out col0+0 <- in col0+d-6
        acc[i].y = fmaf(w, z[d + 3], acc[i].y);
        acc[i].z = fmaf(w, z[d + 4], acc[i].z);
        acc[i].w = fmaf(w, z[d + 5], acc[i].w);
      }
    }
  }

  if (ocol < TLEN - STRIP) {   // groups are exact multiples of 4: all-or-nothing
    #pragma unroll
    for (int i = 0; i < 8; ++i)
      *(float4*)(out + i*TLEN + ocol) = acc[i];
  }
}

extern "C" void kernel_launch(void* const* d_in, const int* in_sizes, int n_in,
                              void* d_out, int out_size, void* d_ws, size_t ws_size,
                              hipStream_t stream)
{
  (void)in_sizes; (void)n_in; (void)out_size; (void)ws_size;
  const float* xs = (const float*)d_in[0];
  const float* ys = (const float*)d_in[1];
  const float* F  = (const float*)d_in[2];
  const float* H  = (const float*)d_in[3];
  const float* Q  = (const float*)d_in[4];
  const float* R  = (const float*)d_in[5];
  const float* ga = (const float*)d_in[6];
  float* ws  = (float*)d_ws;     // [0, 12*13*8): band weights, layout [k][d][i]
  float* out = (float*)d_out;
  band_and_edges<<<15, 256, 0, stream>>>(xs, ys, F, H, Q, R, ga, ws, out);
  kgm_conv<<<NCONV, CT, 0, stream>>>(xs, ys, ws, out);
}

// Round 12
// 49.947 us; speedup vs baseline: 1.0657x; 1.0385x over previous
//
#include <hip/hip_runtime.h>

#define TLEN   500000
#define NITER  100
#define DHALF  6                  // band half-width; W_d ~ 0.135/d! -> d=7 term ~2.7e-5
#define NOFF   (2*DHALF+1)        // 13 offsets
#define STRIP  20                 // edge strip width
#define EWIN   32                 // edge window (32 cols x 8 rows = 256 lanes)
#define CT     256                // conv threads
#define CCPT   4                  // cols per thread
#define NCONV  (((TLEN - 2*STRIP)/CCPT + CT - 1) / CT)   // 489
#define WROW   128                // padded weights per source-row k

// ============ K1: band weights (blocks 0-11) + edge strips (blocks 12,13) ============
// One lane per (column-state, output-row i). Each lane keeps only row i of
// Cm/P/Fu (23 coefficients) in registers; column states live in a ping-ponged
// LDS buffer with one barrier per iteration.
__global__ __launch_bounds__(256) void band_and_edges(
    const float* __restrict__ xs, const float* __restrict__ ys,
    const float* __restrict__ F, const float* __restrict__ H,
    const float* __restrict__ Q, const float* __restrict__ R,
    const float* __restrict__ gam,
    float* __restrict__ wout,            // d_ws: 12*WROW floats, layout [k][d*8+i], pad 0
    float* __restrict__ out)
{
  __shared__ double dQaug[8][16];
  __shared__ double dRaug[4][8];
  __shared__ double dFtQi[64], dHtRi[32], dA1[64], dB2[64];
  __shared__ float fmats[224];
  __shared__ __align__(16) float st[2][34][8];   // ping-pong column states

  const int tid = threadIdx.x;
  const int b   = blockIdx.x;
  const int r8  = (tid >> 3) & 7;
  const int c8  = tid & 7;

  // ---------- double-precision operator construction (redundant per block) ----------
  if (tid < 64) {
    dQaug[r8][c8]     = (double)Q[r8*8 + c8];
    dQaug[r8][c8 + 8] = (c8 == r8) ? 1.0 : 0.0;
  } else if (tid < 96) {
    int t = tid - 64, rr = t >> 3, cr = t & 7;
    dRaug[rr][cr] = (cr < 4) ? (double)R[rr*4 + cr] : ((cr - 4 == rr) ? 1.0 : 0.0);
  }
  __syncthreads();
  for (int col = 0; col < 8; ++col) {      // Gauss-Jordan (Q,R SPD: no pivoting)
    double piv = 1, fq = 0, p1 = 0, p2 = 0, m1 = 0, m2 = 0;
    double rpiv = 1, frr = 0, pr = 0, mr = 0;
    const bool doQ = tid < 64;
    const bool doR = (tid >= 64 && tid < 96 && col < 4);
    if (doQ) {
      piv = dQaug[col][col]; fq = dQaug[r8][col];
      p1 = dQaug[col][c8];   p2 = dQaug[col][c8 + 8];
      m1 = dQaug[r8][c8];    m2 = dQaug[r8][c8 + 8];
    }
    if (doR) {
      int t = tid - 64, rr = t >> 3, cr = t & 7;
      rpiv = dRaug[col][col]; frr = dRaug[rr][col];
      pr = dRaug[col][cr];    mr = dRaug[rr][cr];
    }
    __syncthreads();
    if (doQ) {
      dQaug[r8][c8]     = (r8 == col) ? m1 / piv : m1 - fq * (p1 / piv);
      dQaug[r8][c8 + 8] = (r8 == col) ? m2 / piv : m2 - fq * (p2 / piv);
    }
    if (doR) {
      int t = tid - 64, rr = t >> 3, cr = t & 7;
      dRaug[rr][cr] = (rr == col) ? mr / rpiv : mr - frr * (pr / rpiv);
    }
    __syncthreads();
  }
  if (tid < 64) {
    double s = 0.0;
    #pragma unroll
    for (int k = 0; k < 8; ++k) s += (double)F[k*8 + r8] * dQaug[k][c8 + 8];
    dFtQi[r8*8 + c8] = s;
    dA1[r8*8 + c8] = (c8 == 0) ? 0.0 : -dQaug[r8][c8 + 8];
  } else if (tid < 96) {
    int t = tid - 64, i = t >> 2, j = t & 3;
    double s = 0.0;
    #pragma unroll
    for (int k = 0; k < 4; ++k) s += (double)H[k*8 + i] * dRaug[k][j + 4];
    dHtRi[i*4 + j] = s;
  }
  __syncthreads();
  if (tid < 64) dB2[r8*8 + c8] = (c8 == 7) ? 0.0 : dFtQi[r8*8 + c8];
  __syncthreads();
  {
    const double g = (double)gam[0];
    if (tid < 64) {
      double sp = 0.0;
      #pragma unroll
      for (int k = 0; k < 8; ++k) sp -= dA1[r8*8 + k] * (double)F[k*8 + c8];
      double t2 = dA1[r8*8 + c8];
      #pragma unroll
      for (int k = 0; k < 8; ++k) t2 -= dB2[r8*8 + k] * (double)F[k*8 + c8];
      #pragma unroll
      for (int k = 0; k < 4; ++k) t2 -= dHtRi[r8*4 + k] * (double)H[k*8 + c8];
      fmats[       c8*8 + r8] = (float)(((r8 == c8) ? 1.0 : 0.0) + g * t2);
      fmats[ 64 +  c8*8 + r8] = (float)(g * sp);
      fmats[128 +  c8*8 + r8] = (float)(g * dB2[r8*8 + c8]);
    } else if (tid < 96) {
      int t = tid - 64, i = t >> 2, j = t & 3;
      fmats[192 + j*8 + i] = (float)(g * dHtRi[i*4 + j]);
    }
  }
  __syncthreads();

  // ---------- per-lane coefficient rows (23 registers) ----------
  const int i = tid & 7;       // output row owned by this lane
  const int g = tid >> 3;      // group: slot (band) or column (edge)
  float cmr[8], pmr[8], fur[7];
  #pragma unroll
  for (int k = 0; k < 8; ++k) {
    cmr[k] = fmats[       k*8 + i];
    pmr[k] = fmats[ 64 +  k*8 + i];
    if (k < 7) fur[k] = fmats[128 + k*8 + i];
  }
  float* const stf = (float*)st;
  const int BUF = 34*8;

  if (b < 12) {
    // ---- band recurrence: W'_s = Cm*W_s + P*W_{s+1} + Fu*W_{s-1}, guards at 0, NOFF+1 ----
    const int c = b;                    // source column 0..11 (8..11 = y columns)
    const bool act = tid < NOFF*8;      // 13 slots x 8 rows
    const int s = g + 1;                // slot 1..13
    for (int idx = tid; idx < 2*BUF; idx += 256) stf[idx] = 0.0f;
    __syncthreads();
    if (act && c < 8 && s == DHALF + 1 && i == c) st[0][s][i] = 1.0f;   // W_0 = I
    const float seed = (act && c >= 8 && s == DHALF + 1) ? fmats[192 + (c - 8)*8 + i] : 0.0f;
    __syncthreads();
    int p = 0;
    float last = 0.0f;
    #pragma unroll 1
    for (int it = 0; it < NITER; ++it) {
      if (act) {
        const float* sp_ = stf + p*BUF;
        const float4 o0 = *(const float4*)(sp_ + s*8);
        const float4 o1 = *(const float4*)(sp_ + s*8 + 4);
        const float4 u0 = *(const float4*)(sp_ + (s + 1)*8);
        const float4 u1 = *(const float4*)(sp_ + (s + 1)*8 + 4);
        const float4 d0 = *(const float4*)(sp_ + (s - 1)*8);
        const float4 d1 = *(const float4*)(sp_ + (s - 1)*8 + 4);
        float a0 = seed, a1 = 0.0f, a2 = 0.0f;
        a0 = fmaf(cmr[0], o0.x, a0); a0 = fmaf(cmr[1], o0.y, a0);
        a0 = fmaf(cmr[2], o0.z, a0); a0 = fmaf(cmr[3], o0.w, a0);
        a0 = fmaf(cmr[4], o1.x, a0); a0 = fmaf(cmr[5], o1.y, a0);
        a0 = fmaf(cmr[6], o1.z, a0); a0 = fmaf(cmr[7], o1.w, a0);
        a1 = fmaf(pmr[0], u0.x, a1); a1 = fmaf(pmr[1], u0.y, a1);
        a1 = fmaf(pmr[2], u0.z, a1); a1 = fmaf(pmr[3], u0.w, a1);
        a1 = fmaf(pmr[4], u1.x, a1); a1 = fmaf(pmr[5], u1.y, a1);
        a1 = fmaf(pmr[6], u1.z, a1); a1 = fmaf(pmr[7], u1.w, a1);
        a2 = fmaf(fur[0], d0.x, a2); a2 = fmaf(fur[1], d0.y, a2);
        a2 = fmaf(fur[2], d0.z, a2); a2 = fmaf(fur[3], d0.w, a2);
        a2 = fmaf(fur[4], d1.x, a2); a2 = fmaf(fur[5], d1.y, a2);
        a2 = fmaf(fur[6], d1.z, a2);
        last = a0 + a1 + a2;
        stf[(p^1)*BUF + s*8 + i] = last;
      }
      __syncthreads();
      p ^= 1;
    }
    if (act) wout[c*WROW + (s - 1)*8 + i] = last;     // [k][d*8+i]
    if (tid >= NOFF*8 && tid < WROW) wout[c*WROW + tid] = 0.0f;   // zero pad
    return;
  }

  // ---- edge strips: 32 columns x 8 rows, true clamp at the outer boundary ----
  const bool left = (b == 12);
  const int col  = g;                                    // 0..31
  const int gcol = left ? col : (TLEN - EWIN + col);
  const int sL = (col > 0) ? col - 1 : 0;                // replicate at window edge
  const int sR = (col < EWIN - 1) ? col + 1 : EWIN - 1;
  const float xv = xs[i*TLEN + gcol];
  float gyv;
  {
    gyv = fmats[192 +      i] * ys[0*TLEN + gcol];
    gyv = fmaf(fmats[192 +  8 + i], ys[1*TLEN + gcol], gyv);
    gyv = fmaf(fmats[192 + 16 + i], ys[2*TLEN + gcol], gyv);
    gyv = fmaf(fmats[192 + 24 + i], ys[3*TLEN + gcol], gyv);
  }
  st[0][col][i] = xv;
  __syncthreads();
  int p = 0;
  float last = xv;
  #pragma unroll 1
  for (int it = 0; it < NITER; ++it) {
    const float* sp_ = stf + p*BUF;
    const float4 o0 = *(const float4*)(sp_ + col*8);
    const float4 o1 = *(const float4*)(sp_ + col*8 + 4);
    const float4 l0 = *(const float4*)(sp_ + sL*8);      // x_{t-1}
    const float4 l1 = *(const float4*)(sp_ + sL*8 + 4);
    const float4 q0 = *(const float4*)(sp_ + sR*8);      // x_{t+1}
    const float4 q1 = *(const float4*)(sp_ + sR*8 + 4);
    float a0 = gyv, a1 = 0.0f, a2 = 0.0f;
    a0 = fmaf(cmr[0], o0.x, a0); a0 = fmaf(cmr[1], o0.y, a0);
    a0 = fmaf(cmr[2], o0.z, a0); a0 = fmaf(cmr[3], o0.w, a0);
    a0 = fmaf(cmr[4], o1.x, a0); a0 = fmaf(cmr[5], o1.y, a0);
    a0 = fmaf(cmr[6], o1.z, a0); a0 = fmaf(cmr[7], o1.w, a0);
    a1 = fmaf(pmr[0], l0.x, a1); a1 = fmaf(pmr[1], l0.y, a1);
    a1 = fmaf(pmr[2], l0.z, a1); a1 = fmaf(pmr[3], l0.w, a1);
    a1 = fmaf(pmr[4], l1.x, a1); a1 = fmaf(pmr[5], l1.y, a1);
    a1 = fmaf(pmr[6], l1.z, a1); a1 = fmaf(pmr[7], l1.w, a1);
    a2 = fmaf(fur[0], q0.x, a2); a2 = fmaf(fur[1], q0.y, a2);
    a2 = fmaf(fur[2], q0.z, a2); a2 = fmaf(fur[3], q0.w, a2);
    a2 = fmaf(fur[4], q1.x, a2); a2 = fmaf(fur[5], q1.y, a2);
    a2 = fmaf(fur[6], q1.z, a2);
    last = a0 + a1 + a2;
    stf[(p^1)*BUF + col*8 + i] = last;
    __syncthreads();
    p ^= 1;
  }
  if (left ? (col < STRIP) : (col >= EWIN - STRIP)) out[i*TLEN + gcol] = last;
}

// ============ K2: interior band convolution — readlane weight broadcast ============
// Per k: two coalesced loads put the 104 weights of source-row k into lanes
// (wA lanes 0-63 = w[0..64), wB lanes 0-39 = w[64..104)); each scalar weight is
// then broadcast via v_readlane (compile-time lane index -> SGPR) feeding FMAs.
__global__ __launch_bounds__(CT) void kgm_conv(
    const float* __restrict__ xs, const float* __restrict__ ys,
    const float* __restrict__ wq, float* __restrict__ out)
{
  const int tid  = threadIdx.x;
  const int lane = tid & 63;
  const int ocol = STRIP + (blockIdx.x * CT + tid) * CCPT;
  const int col0 = (ocol <= TLEN - STRIP - CCPT) ? ocol : (TLEN - STRIP - CCPT);

  float4 acc[8];
  #pragma unroll
  for (int i = 0; i < 8; ++i) acc[i] = make_float4(0.f, 0.f, 0.f, 0.f);

  #pragma unroll 2
  for (int k = 0; k < 12; ++k) {
    const float* src = ((k < 8) ? (xs + k*TLEN) : (ys + (k-8)*TLEN)) + col0;
    const float wA = wq[k*WROW + lane];
    const float wB = wq[k*WROW + 64 + lane];
    // 20-float window [col0-8, col0+12); col0 % 4 == 0 so all loads 16B-aligned
    float z[20];
    #pragma unroll
    for (int j = 0; j < 5; ++j) {
      float4 v = *(const float4*)(src - 8 + 4*j);
      z[4*j] = v.x; z[4*j + 1] = v.y; z[4*j + 2] = v.z; z[4*j + 3] = v.w;
    }
    #pragma unroll
    for (int d = 0; d < NOFF; ++d) {
      #pragma unroll
      for (int i = 0; i < 8; ++i) {
        constexpr int dummy = 0; (void)dummy;
        const int j = d*8 + i;                       // compile-time constant
        const int wi = __builtin_amdgcn_readlane(
            __float_as_int((j < 64) ? wA : wB), j & 63);
        const float w = __int_as_float(wi);
        acc[i].x = fmaf(w, z[d + 2], acc[i].x);      // out col0+0 <- in col0+d-6
        acc[i].y = fmaf(w, z[d + 3], acc[i].y);
        acc[i].z = fmaf(w, z[d + 4], acc[i].z);
        acc[i].w = fmaf(w, z[d + 5], acc[i].w);
      }
    }
  }

  if (ocol < TLEN - STRIP) {   // groups tile exactly (499960 % 4 == 0): all-or-nothing
    #pragma unroll
    for (int i = 0; i < 8; ++i)
      *(float4*)(out + i*TLEN + ocol) = acc[i];
  }
}

extern "C" void kernel_launch(void* const* d_in, const int* in_sizes, int n_in,
                              void* d_out, int out_size, void* d_ws, size_t ws_size,
                              hipStream_t stream)
{
  (void)in_sizes; (void)n_in; (void)out_size; (void)ws_size;
  const float* xs = (const float*)d_in[0];
  const float* ys = (const float*)d_in[1];
  const float* F  = (const float*)d_in[2];
  const float* H  = (const float*)d_in[3];
  const float* Q  = (const float*)d_in[4];
  const float* R  = (const float*)d_in[5];
  const float* ga = (const float*)d_in[6];
  float* ws  = (float*)d_ws;     // [0, 12*WROW): band weights, layout [k][d*8+i] pad-0
  float* out = (float*)d_out;
  band_and_edges<<<14, 256, 0, stream>>>(xs, ys, F, H, Q, R, ga, ws, out);
  kgm_conv<<<NCONV, CT, 0, stream>>>(xs, ys, ws, out);
}